// Round 19
// baseline (205.381 us; speedup 1.0000x reference)
//
#include <hip/hip_runtime.h>
#include <stdint.h>

#define M_DIM 8192
#define N_DIM 4096
#define K_DIM 4096
#define CBN   (K_DIM/8)   // 512 column groups per row

typedef __attribute__((ext_vector_type(4)))  int   i32x4;
typedef __attribute__((ext_vector_type(16))) char  i8x16;
typedef __attribute__((ext_vector_type(2)))  unsigned int u32x2;

#define AS_GLOBAL(p) (const __attribute__((address_space(1))) void*)(p)
#define AS_LDS(p)    (__attribute__((address_space(3))) void*)(p)

// ---------------------------------------------------------------------------
// Kernel 1: per (ob, cb) pick top-4 columns (of 8) by L1 mass over 64 rows.
// (unchanged, verified)
// ---------------------------------------------------------------------------
__global__ __launch_bounds__(256) void venom_sel(const float* __restrict__ W,
                                                 uint16_t* __restrict__ sel) {
    int t   = threadIdx.x;
    int ob  = blockIdx.x;
    int col = blockIdx.y * 256 + t;
    const float* p = W + (size_t)(ob * 64) * K_DIM + col;
    double s = 0.0;
    #pragma unroll 16
    for (int r = 0; r < 64; ++r) s += fabsf(p[(size_t)r * K_DIM]);

    int lane = t & 63;
    int base = lane & ~7;
    double sc[8];
    #pragma unroll
    for (int j = 0; j < 8; ++j) sc[j] = __shfl(s, base + j, 64);

    uint32_t packed = 0;
    #pragma unroll
    for (int c = 0; c < 8; ++c) {
        int rank = 0;
        #pragma unroll
        for (int j = 0; j < 8; ++j)
            rank += (sc[j] > sc[c]) || (sc[j] == sc[c] && j < c);
        if (rank < 4) packed |= (uint32_t)c << (4 * rank);
    }
    if ((lane & 7) == 0) {
        int cb = col >> 3;
        sel[ob * CBN + cb] = (uint16_t)packed;
    }
}

// ---------------------------------------------------------------------------
// Kernel 2: masked weight -> COMPRESSED int8 (2 values + 2 indices per 8-K
// group, one u32) with per-output-row symmetric scale. Same keep logic and
// quantization as the verified dense version -> identical numerics.
// Layout: comp[(o>>8)*64 + s][r = o&255][g] u32, i.e. 8KB contiguous per
// (bn-block, K-slice) -> GEMM stages one slice with coalesced dwordx4 loads.
// ---------------------------------------------------------------------------
__global__ __launch_bounds__(256) void venom_packq(const float* __restrict__ W,
                                                   const uint16_t* __restrict__ sel,
                                                   uint32_t* __restrict__ comp,
                                                   float* __restrict__ sw) {
    __shared__ float red[4];
    int o = blockIdx.x;
    const float* rowp = W + (size_t)o * K_DIM;
    float mv[16];
    uint32_t keeps[2];
    float m = 0.0f;
    #pragma unroll
    for (int h = 0; h < 2; ++h) {
        int cb = threadIdx.x * 2 + h;
        uint32_t pk = sel[(o >> 6) * CBN + cb];
        const float* p = rowp + cb * 8;
        float4 a = *(const float4*)p;
        float4 b = *(const float4*)(p + 4);
        float w[8] = {a.x, a.y, a.z, a.w, b.x, b.y, b.z, b.w};
        int   c[4]; float v[4];
        #pragma unroll
        for (int pz = 0; pz < 4; ++pz) {
            c[pz] = (pk >> (4 * pz)) & 7;
            v[pz] = fabsf(w[c[pz]]);
        }
        uint32_t keep = 0;
        #pragma unroll
        for (int pz = 0; pz < 4; ++pz) {
            int cnt = 0;
            #pragma unroll
            for (int q = 0; q < 4; ++q)
                cnt += (v[q] > v[pz]) || (v[q] == v[pz] && q < pz);
            if (cnt < 2) keep |= 1u << c[pz];
        }
        keeps[h] = keep;
        #pragma unroll
        for (int j = 0; j < 8; ++j) {
            float x = ((keep >> j) & 1) ? w[j] : 0.0f;
            mv[h * 8 + j] = x;
            m = fmaxf(m, fabsf(x));
        }
    }
    #pragma unroll
    for (int off = 32; off >= 1; off >>= 1) m = fmaxf(m, __shfl_xor(m, off, 64));
    int lane = threadIdx.x & 63, wid = threadIdx.x >> 6;
    if (lane == 0) red[wid] = m;
    __syncthreads();
    m = fmaxf(fmaxf(red[0], red[1]), fmaxf(red[2], red[3]));
    float inv = m > 0.0f ? 127.0f / m : 0.0f;

    int blk = o >> 8, r = o & 255;
    #pragma unroll
    for (int h = 0; h < 2; ++h) {
        int cb = threadIdx.x * 2 + h;
        uint32_t keep = keeps[h];
        uint32_t i0 = (uint32_t)__builtin_ctz(keep);
        uint32_t i1 = 31u - (uint32_t)__builtin_clz(keep);
        float q0f = rintf(mv[h * 8 + i0] * inv);
        float q1f = rintf(mv[h * 8 + i1] * inv);
        q0f = fminf(127.0f, fmaxf(-127.0f, q0f));
        q1f = fminf(127.0f, fmaxf(-127.0f, q1f));
        uint32_t q0 = (uint32_t)((int)q0f) & 0xffu;
        uint32_t q1 = (uint32_t)((int)q1f) & 0xffu;
        uint32_t cw = q0 | (q1 << 8) | (i0 << 16) | (i1 << 24);
        int s = cb >> 3, g = cb & 7;
        comp[((size_t)(blk * 64 + s) * 256 + r) * 8 + g] = cw;
    }
    if (threadIdx.x == 0) sw[o] = m > 0.0f ? m / 127.0f : 1.0f;
}

// ---------------------------------------------------------------------------
// Kernel 3: x f32 -> int8 with per-row symmetric scale. (unchanged)
// ---------------------------------------------------------------------------
__global__ __launch_bounds__(256) void xq_kernel(const float* __restrict__ X,
                                                 int8_t* __restrict__ Xq,
                                                 float* __restrict__ sx) {
    __shared__ float red[4];
    int row = blockIdx.x;
    const float4* p = (const float4*)(X + (size_t)row * K_DIM) + threadIdx.x * 4;
    float4 v0 = p[0], v1 = p[1], v2 = p[2], v3 = p[3];
    float vv[16] = {v0.x, v0.y, v0.z, v0.w, v1.x, v1.y, v1.z, v1.w,
                    v2.x, v2.y, v2.z, v2.w, v3.x, v3.y, v3.z, v3.w};
    float m = 0.0f;
    #pragma unroll
    for (int j = 0; j < 16; ++j) m = fmaxf(m, fabsf(vv[j]));
    #pragma unroll
    for (int off = 32; off >= 1; off >>= 1) m = fmaxf(m, __shfl_xor(m, off, 64));
    int lane = threadIdx.x & 63, wid = threadIdx.x >> 6;
    if (lane == 0) red[wid] = m;
    __syncthreads();
    m = fmaxf(fmaxf(red[0], red[1]), fmaxf(red[2], red[3]));
    float inv = m > 0.0f ? 127.0f / m : 0.0f;

    i8x16 q;
    #pragma unroll
    for (int j = 0; j < 16; ++j) {
        float qq = rintf(vv[j] * inv);
        qq = fminf(127.0f, fmaxf(-127.0f, qq));
        q[j] = (char)(int)qq;
    }
    *(i8x16*)(Xq + (size_t)row * K_DIM + threadIdx.x * 16) = q;
    if (threadIdx.x == 0) sx[row] = m > 0.0f ? m / 127.0f : 1.0f;
}

// ---------------------------------------------------------------------------
// Kernel 4: 256x256 int8 GEMM with COMPRESSED-B staging. All variants hit the
// same ~13 B/cy/CU vmem-ingest wall (staging-BW-bound); this cuts staged
// bytes 32->24 KB/slice: A staged dense via gload_lds (4 regions, lead 2);
// B staged COMPRESSED (1 coalesced dwordx4/thread -> reg dbuf cA/cB), then
// expanded (byte placement, bit-identical to dense wq) and ds_write'd into
// the round-13 swizzled dense-B layout (2 parity regions). MFMA/read path =
// round 13 verbatim.
// SP s: { 12 ds_read (A region s&3, denseB parity s&1) | stageA(s+2) |
//         compload(s+2)->CN | lgkm(4) | 16 MFMA Mh0 | lgkm(0) | 16 MFMA Mh1 |
//         vmcnt(3) | EXPAND(CC=comp(s+1)) -> denseB parity (s+1)&1 |
//         lgkm(0) | BAR }
// Ledger: trio(s) = [sA(s) x2, comp(s)] issued @s-2. vmcnt(3)@s-end drains
//   trio(s+1) -> A-reads@s+1 and expand-src comp(s+1) covered (+reg autowait).
//   denseB(s) written by EXPAND@s-1, lgkm(0)-drained + BAR. W-after-R:
//   EXPAND@s overwrites parity of slice s-1, whose reads drained @s-1 before
//   BAR@s-1; stageA@s overwrites region of s-2, read @s-2. Tail: s=62
//   vmcnt(0) (drains trio(63)); s=63 no stage/expand/ckpt.
// Epilogue: C = sx[row]*sw[col]*acc + bias. XCD swizzle; 0 bank conflicts.
// ---------------------------------------------------------------------------
__global__ __launch_bounds__(512, 2) void gemm256_i8(const int8_t* __restrict__ A,
                                                     const uint32_t* __restrict__ comp,
                                                     const float* __restrict__ sx,
                                                     const float* __restrict__ sw,
                                                     const float* __restrict__ bias,
                                                     float* __restrict__ C) {
    __shared__ __align__(16) unsigned char smem[98304]; // A:4x16KB@0, denseB:2x16KB@64K

    int t    = threadIdx.x;
    int wid  = t >> 6;
    int lane = t & 63;
    int l16  = lane & 15;
    int lk   = lane >> 4;
    int wm   = wid >> 2;     // wave row-half (128 rows)
    int wn   = wid & 3;      // wave col-quarter (64 cols)

    // XCD-aware bijective swizzle (512 blocks % 8 == 0)
    int bid = blockIdx.x;
    int swz = (bid & 7) * ((int)gridDim.x >> 3) + (bid >> 3);
    int bm  = swz >> 4;
    int bn  = swz & 15;

    // A staging: thread t covers row r=t>>2 (and r+128); stored 16B chunk t&3
    // holds logical chunk (t&3)^((t>>3)&3)
    int gch = ((t & 3) ^ ((t >> 3) & 3)) * 16;
    const int8_t* agbase = A + (size_t)(bm * 256 + (t >> 2)) * K_DIM + gch;

    auto stageA2 = [&](int slice) {
        const int8_t* ga = agbase + slice * 64;
        char* la = (char*)smem + (slice & 3) * 16384 + wid * 1024;
        __builtin_amdgcn_global_load_lds(AS_GLOBAL(ga), AS_LDS(la), 16, 0, 0);
        __builtin_amdgcn_global_load_lds(AS_GLOBAL(ga + (size_t)128 * K_DIM), AS_LDS(la + 8192), 16, 0, 0);
    };

    // compressed-B: slice s is 8KB contiguous at comp + (bn*64+s)*2048 u32;
    // thread t loads 16B at +t*16  (row r=t>>1, groups (t&1)*4..+3)
    const char* cmpb = (const char*)comp + (size_t)(bn * 64) * 8192 + t * 16;

    // read-side: row R = base+l16, 16B chunk lk -> phys chunk lk^((l16>>1)&3)
    int koff = ((lk ^ ((l16 >> 1) & 3)) << 4);
    const char* ardb = (const char*)smem + (wm * 128 + l16) * 64 + koff;
    const char* brdb = (const char*)smem + 65536 + (wn * 64 + l16) * 64 + koff;

    // expand write base: row r=t>>1, swizzle key (r>>1)&3 = (t>>2)&3
    char* expb = (char*)smem + 65536 + (t >> 1) * 64 + ((t & 1) << 5);
    int   xk   = (t >> 2) & 3;

    i32x4 acc[8][4] = {};
    i32x4 af0[4], af1[4], bfr[4];
    i32x4 cAr, cBr;

#define LGKM(N) { asm volatile("s_waitcnt lgkmcnt(" #N ")" ::: "memory");            \
                  __builtin_amdgcn_sched_barrier(0); }
#define CKPT3() { asm volatile("s_waitcnt vmcnt(3)" ::: "memory");                   \
                  __builtin_amdgcn_sched_barrier(0); }
#define CKPT0() { asm volatile("s_waitcnt vmcnt(0)" ::: "memory");                   \
                  __builtin_amdgcn_sched_barrier(0); }
#define BAR()   { __builtin_amdgcn_s_barrier(); __builtin_amdgcn_sched_barrier(0); }

    // expand comp word -> 8 dense bytes at group g (byte placement; zeros
    // elsewhere). Writes parity EP region. g = (t&1)*4 + k.
#define EXPAND(CC_, EP)                                                              \
    {                                                                                \
        _Pragma("unroll")                                                            \
        for (int k = 0; k < 4; ++k) {                                                \
            uint32_t cw = (uint32_t)CC_[k];                                          \
            uint32_t v0 = cw & 0xffu, v1 = (cw >> 8) & 0xffu;                        \
            uint32_t i0 = (cw >> 16) & 0xffu, i1 = cw >> 24;                         \
            uint32_t a0 = v0 << ((i0 & 3u) << 3), a1 = v1 << ((i1 & 3u) << 3);       \
            uint32_t lo = (i0 < 4u ? a0 : 0u) | (i1 < 4u ? a1 : 0u);                 \
            uint32_t hi = (i0 < 4u ? 0u : a0) | (i1 < 4u ? 0u : a1);                 \
            int g = ((t & 1) << 2) + k;                                              \
            u32x2 val; val[0] = lo; val[1] = hi;                                     \
            *(u32x2*)(expb + (EP) * 16384 + ((((g >> 1) ^ xk) << 4) + ((g & 1) << 3)) \
                      - ((t & 1) << 5)) = val;                                       \
        }                                                                            \
    }
    // note: expb pre-adds (t&1)*32 then we subtract it and use g-based chunk
    // addressing; net addr = 65536 + EP*16384 + r*64 + physchunk*16 + (g&1)*8.

    // SP. RN: A region (s&3). BP: denseB parity (s&1). SS: slice s+2.
    // CC: comp(s+1) regs (expanded at end). CN: dest for comp(s+2).
    // DOSTAGE; CK: 3/1/0(none); DOEXP; EP = (s+1)&1.
#define SP(RN, BP, CC, CN, SS, DOSTAGE, CK, DOEXP, EP)                               \
    {                                                                                \
        const char* abase = ardb + (RN) * 16384;                                     \
        const char* bbase = brdb + (BP) * 16384;                                     \
        _Pragma("unroll")                                                            \
        for (int g = 0; g < 4; ++g) bfr[g] = *(const i32x4*)(bbase + g * 1024);      \
        _Pragma("unroll")                                                            \
        for (int i = 0; i < 4; ++i) af0[i] = *(const i32x4*)(abase + i * 1024);      \
        _Pragma("unroll")                                                            \
        for (int i = 0; i < 4; ++i) af1[i] = *(const i32x4*)(abase + 4096 + i * 1024); \
        if (DOSTAGE) {                                                               \
            stageA2(SS);                                                             \
            CN = *(const i32x4*)(cmpb + (SS) * 8192);                                \
        }                                                                            \
        LGKM(4)                                                                      \
        __builtin_amdgcn_s_setprio(1);                                               \
        _Pragma("unroll")                                                            \
        for (int i = 0; i < 4; ++i)                                                  \
            _Pragma("unroll")                                                        \
            for (int g = 0; g < 4; ++g)                                              \
                acc[i][g] = __builtin_amdgcn_mfma_i32_16x16x64_i8(af0[i], bfr[g], acc[i][g], 0, 0, 0); \
        __builtin_amdgcn_s_setprio(0);                                               \
        __builtin_amdgcn_sched_barrier(0);                                           \
        LGKM(0)                                                                      \
        __builtin_amdgcn_s_setprio(1);                                               \
        _Pragma("unroll")                                                            \
        for (int i = 0; i < 4; ++i)                                                  \
            _Pragma("unroll")                                                        \
            for (int g = 0; g < 4; ++g)                                              \
                acc[4+i][g] = __builtin_amdgcn_mfma_i32_16x16x64_i8(af1[i], bfr[g], acc[4+i][g], 0, 0, 0); \
        __builtin_amdgcn_s_setprio(0);                                               \
        __builtin_amdgcn_sched_barrier(0);                                           \
        if ((CK) == 3) { CKPT3() } else if ((CK) == 1) { CKPT0() }                   \
        if (DOEXP) { EXPAND(CC, EP) LGKM(0) }                                        \
        BAR()                                                                        \
    }

    // prologue: trio(0), trio(1); drain trio(0); expand comp(0)->parity 0.
    stageA2(0);
    cAr = *(const i32x4*)(cmpb + 0);
    stageA2(1);
    cBr = *(const i32x4*)(cmpb + 8192);
    CKPT3()
    EXPAND(cAr, 0)
    LGKM(0)
    BAR()

    // s = 0..59: 4-unrolled. CC holds comp(s+1): s even -> cBr, s odd -> cAr.
    for (int s4 = 0; s4 < 15; ++s4) {
        int s = s4 * 4;
        SP(0, 0, cBr, cAr, s + 2, 1, 3, 1, 1)
        SP(1, 1, cAr, cBr, s + 3, 1, 3, 1, 0)
        SP(2, 0, cBr, cAr, s + 4, 1, 3, 1, 1)
        SP(3, 1, cAr, cBr, s + 5, 1, 3, 1, 0)
    }
    SP(0, 0, cBr, cAr, 62, 1, 3, 1, 1)   // s=60
    SP(1, 1, cAr, cBr, 63, 1, 3, 1, 0)   // s=61
    SP(2, 0, cBr, cAr, 0,  0, 1, 1, 1)   // s=62: vmcnt(0) drains trio(63); expand comp(63)
    SP(3, 1, cAr, cBr, 0,  0, 0, 0, 0)   // s=63: MFMA only

    // epilogue: C/D layout col = lane&15, row = (lane>>4)*4 + reg.
    int    colb = bn * 256 + wn * 64;
    size_t rowb = (size_t)bm * 256 + wm * 128 + (lk << 2);
    float sxv[8][4];
    #pragma unroll
    for (int f = 0; f < 8; ++f)
        #pragma unroll
        for (int rg = 0; rg < 4; ++rg)
            sxv[f][rg] = sx[rowb + f * 16 + rg];
    #pragma unroll
    for (int g = 0; g < 4; ++g) {
        int col = colb + g * 16 + l16;
        float scw = sw[col];
        float bv  = bias[col];
        #pragma unroll
        for (int f = 0; f < 8; ++f) {
            size_t r0 = rowb + f * 16;
            #pragma unroll
            for (int rg = 0; rg < 4; ++rg)
                C[(r0 + rg) * N_DIM + col] = (float)acc[f][g][rg] * (sxv[f][rg] * scw) + bv;
        }
    }
}

extern "C" void kernel_launch(void* const* d_in, const int* in_sizes, int n_in,
                              void* d_out, int out_size, void* d_ws, size_t ws_size,
                              hipStream_t stream) {
    const float* x    = (const float*)d_in[0];
    const float* W    = (const float*)d_in[1];
    const float* bias = (const float*)d_in[2];
    float* out = (float*)d_out;

    char* ws = (char*)d_ws;
    int8_t*   xq   = (int8_t*)ws;                                            // 32 MB
    uint32_t* comp = (uint32_t*)(ws + (size_t)M_DIM * K_DIM);                // 8 MB
    uint16_t* sel  = (uint16_t*)(ws + (size_t)M_DIM * K_DIM
                                    + (size_t)N_DIM * CBN * 4);              // 64 KB
    float*    sx   = (float*)((char*)sel + (size_t)(M_DIM / 64) * CBN * 2);  // 32 KB
    float*    sw   = (float*)((char*)sx + (size_t)M_DIM * 4);                // 16 KB

    venom_sel  <<<dim3(64, 16), 256, 0, stream>>>(W, sel);
    venom_packq<<<dim3(N_DIM), 256, 0, stream>>>(W, sel, comp, sw);
    xq_kernel  <<<dim3(M_DIM), 256, 0, stream>>>(x, xq, sx);
    gemm256_i8 <<<dim3((M_DIM / 256) * (N_DIM / 256)), 512, 0, stream>>>(xq, comp, sx, sw, bias, out);
}